// Round 8
// baseline (259.123 us; speedup 1.0000x reference)
//
#include <hip/hip_runtime.h>
#include <math.h>

// EGNN fused kernel, round 8. Register discipline: NO accumulator crosses a
// barrier (r6/r7 spilled because macc+hv+racc overlapped: FETCH 45-946MB).
// Key: e-gate folded into GEMM2 via composite column wv = We2@Winf
//   e_logit = t1@wv + (be2.Winf + binf)   (algebraic identity)
// -> eacc produced by the SAME MFMA phase as macc; sigmoid+shfl+m_i accum all
//    complete inside B2; macc dies before the barrier.
// 4 barriers/tile: B1 GEMM1->P1 | B2 GEMM2+eacc, mask, ->P2, e+m_i (macc dies)
// | B3 stage-loads, GEMM3->P1 | B4 GEMM4->racc, stage-writes, phi+shift.
// Per-thread shift partials reduced once at kernel end. GEMM4 never stored.

#define BB    2
#define NN    512
#define HDIM  64
#define UDIM  128
#define JT    64
#define NTILE (NN / JT)
#define FP    72    // F row pitch (ushort), 144B
#define PP    136   // P row pitch (ushort), 272B

typedef float f32x4 __attribute__((ext_vector_type(4)));
typedef short s16x8 __attribute__((ext_vector_type(8)));

__device__ __forceinline__ ushort f2bf(float f) {          // setup-path only
    union { float f; unsigned u; } v; v.f = f;
    return (ushort)((v.u + 0x7FFFu + ((v.u >> 16) & 1u)) >> 16);
}
__device__ __forceinline__ unsigned pk2(float lo, float hi) {  // bf16 pair pack
    unsigned r;
    asm("v_cvt_pk_bf16_f32 %0, %1, %2" : "=v"(r) : "v"(lo), "v"(hi));
    return r;
}
__device__ __forceinline__ f32x4 MFMA(s16x8 a, s16x8 b, f32x4 c) {
    return __builtin_amdgcn_mfma_f32_16x16x32_bf16(a, b, c, 0, 0, 0);
}
__device__ __forceinline__ float eluf(float v) { return v > 0.f ? v : __expf(v) - 1.f; }

__device__ __forceinline__ void load_wfrags(const float* __restrict__ W, int q, int uc0,
                                            s16x8 (&dst)[4][2]) {
#pragma unroll
    for (int s = 0; s < 4; ++s)
#pragma unroll
        for (int n = 0; n < 2; ++n) {
            s16x8 r;
#pragma unroll
            for (int ii = 0; ii < 8; ++ii)
                r[ii] = (short)f2bf(W[(32 * s + 8 * q + ii) * UDIM + uc0 + n]);
            dst[s][n] = r;
        }
}

// acc[m][n] += A[16m+l15][k]*wB[s][n]; EXTRA: eacc[m] += A*wE[s] (col0 = wv)
template <int KSTEPS, int PITCH, bool EXTRA>
__device__ __forceinline__ void gemm_P(const ushort* __restrict__ P,
                                       const s16x8 (&wB)[KSTEPS][2], const s16x8* wE,
                                       int l15, int q, f32x4 (&acc)[4][2], f32x4* eacc) {
    __builtin_amdgcn_s_setprio(1);
#pragma unroll
    for (int s = 0; s < KSTEPS; ++s) {
        s16x8 a[4];
#pragma unroll
        for (int m = 0; m < 4; ++m)
            a[m] = *(const s16x8*)(P + (16 * m + l15) * PITCH + 32 * s + 8 * q);
#pragma unroll
        for (int m = 0; m < 4; ++m) {
            acc[m][0] = MFMA(a[m], wB[s][0], acc[m][0]);
            acc[m][1] = MFMA(a[m], wB[s][1], acc[m][1]);
            if (EXTRA) eacc[m] = MFMA(a[m], wE[s], eacc[m]);
        }
    }
    __builtin_amdgcn_s_setprio(0);
}

template <bool ELU>
__device__ __forceinline__ void store_P(ushort* __restrict__ P, const f32x4 (&v)[4][2],
                                        int q, int uc0) {
#pragma unroll
    for (int m = 0; m < 4; ++m)
#pragma unroll
        for (int r = 0; r < 4; ++r) {
            const int row = 16 * m + 4 * q + r;
            float a = v[m][0][r], c = v[m][1][r];
            if (ELU) { a = eluf(a); c = eluf(c); }
            *(unsigned*)(P + row * PP + uc0) = pk2(a, c);
        }
}

__global__ __launch_bounds__(256, 2) void egnn_mfma(
    const float* __restrict__ x, const float* __restrict__ h,
    const float* __restrict__ We1, const float* __restrict__ be1,
    const float* __restrict__ We2, const float* __restrict__ be2,
    const float* __restrict__ Winf, const float* __restrict__ binf,
    const float* __restrict__ Wx1, const float* __restrict__ bx1,
    const float* __restrict__ Wx2, const float* __restrict__ bx2,
    const float* __restrict__ Wx3, const float* __restrict__ bx3,
    const float* __restrict__ Wh1, const float* __restrict__ bh1,
    const float* __restrict__ Wh2, const float* __restrict__ bh2,
    const float* __restrict__ Wout, const float* __restrict__ bout,
    float* __restrict__ out) {
    __shared__ ushort F[2][JT][FP];   // double-buffered feat tile (h_j bf16)
    __shared__ ushort P1[JT][PP];
    __shared__ ushort P2[JT][PP];
    __shared__ float normL[2][JT];
    __shared__ float diffL[2][JT][3];
    __shared__ float bias1L[UDIM];
    __shared__ float wvL[UDIM];       // We2 @ Winf
    __shared__ float ebiasL;          // be2.Winf + binf
    __shared__ float shiftL[4][3];
    __shared__ float catL[UDIM + HDIM];
    __shared__ float th1[UDIM], th2[UDIM];

    const int bi = blockIdx.x;
    const int b  = bi >> 9;
    const int i  = bi & (NN - 1);
    const int tid  = threadIdx.x;
    const int lane = tid & 63;
    const int w    = tid >> 6;
    const int l15  = lane & 15;
    const int q    = lane >> 4;
    const int uc0  = 32 * w + 2 * l15;
    const int jr   = tid >> 2, k0 = (tid & 3) * 16;   // staging row/col

    // ---- weight fragments (112 VGPRs) ----
    s16x8 wB1[2][2];                  // We1 rows 1..64 (h_j part)
#pragma unroll
    for (int s = 0; s < 2; ++s)
#pragma unroll
        for (int n = 0; n < 2; ++n) {
            s16x8 r;
#pragma unroll
            for (int ii = 0; ii < 8; ++ii)
                r[ii] = (short)f2bf(We1[(1 + 32 * s + 8 * q + ii) * UDIM + uc0 + n]);
            wB1[s][n] = r;
        }
    s16x8 wB2[4][2], wB3[4][2], wB4[4][2];
    load_wfrags(We2, q, uc0, wB2);
    load_wfrags(Wx1, q, uc0, wB3);
    load_wfrags(Wx2, q, uc0, wB4);

    if (tid < UDIM) {
        float s = be1[tid];
        const float* hi = &h[(b * NN + i) * HDIM];
#pragma unroll 8
        for (int k = 0; k < HDIM; ++k)
            s = fmaf(hi[k], We1[(1 + HDIM + k) * UDIM + tid], s);
        bias1L[tid] = s;              // be1 + h_i @ We1[65:129]
        float v = 0.f;
        const float* w2r = &We2[tid * UDIM];
#pragma unroll 8
        for (int u = 0; u < UDIM; ++u) v = fmaf(w2r[u], Winf[u], v);
        wvL[tid] = v;                 // (We2 @ Winf)[tid]
    }
    if (tid == 0) {
        float s = binf[0];
        for (int u = 0; u < UDIM; ++u) s = fmaf(be2[u], Winf[u], s);
        ebiasL = s;
    }
    const float w0n0 = We1[uc0], w0n1 = We1[uc0 + 1];      // norm row of We1
    const float b2n0 = be2[uc0], b2n1 = be2[uc0 + 1];
    const float bqn0 = bx1[uc0], bqn1 = bx1[uc0 + 1];
    const float brn0 = bx2[uc0], brn1 = bx2[uc0 + 1];
    const float wx30 = Wx3[uc0], wx31 = Wx3[uc0 + 1];
    const float bx30 = bx3[0];
    const float xi0 = x[(b * NN + i) * 3 + 0];
    const float xi1 = x[(b * NN + i) * 3 + 1];
    const float xi2 = x[(b * NN + i) * 3 + 2];

    // ---- prologue: stage tile 0 into buffer 0 ----
    {
        const float* hp = &h[(b * NN + jr) * HDIM + k0];
        const float4 f0 = *(const float4*)hp;
        const float4 f1 = *(const float4*)(hp + 4);
        const float4 f2 = *(const float4*)(hp + 8);
        const float4 f3 = *(const float4*)(hp + 12);
        uint4 pv0, pv1;
        pv0.x = pk2(f0.x, f0.y); pv0.y = pk2(f0.z, f0.w);
        pv0.z = pk2(f1.x, f1.y); pv0.w = pk2(f1.z, f1.w);
        pv1.x = pk2(f2.x, f2.y); pv1.y = pk2(f2.z, f2.w);
        pv1.z = pk2(f3.x, f3.y); pv1.w = pk2(f3.z, f3.w);
        *(uint4*)&F[0][jr][k0]     = pv0;
        *(uint4*)&F[0][jr][k0 + 8] = pv1;
        if (tid < JT) {
            const int j = tid;
            float d0 = x[(b * NN + j) * 3 + 0] - xi0;
            float d1 = x[(b * NN + j) * 3 + 1] - xi1;
            float d2 = x[(b * NN + j) * 3 + 2] - xi2;
            if (j == i) { d0 = 0.f; d1 = 0.f; d2 = 0.f; }
            diffL[0][tid][0] = d0; diffL[0][tid][1] = d1; diffL[0][tid][2] = d2;
            normL[0][tid] = sqrtf(d0 * d0 + d1 * d1 + d2 * d2);
        }
    }
    __syncthreads();                  // bias1L/wvL/ebias/tile-0 visible
    const float b1n0 = bias1L[uc0], b1n1 = bias1L[uc0 + 1];
    const float ebias = ebiasL;
    s16x8 wE[4];                      // composite e-column: col0 = wv
#pragma unroll
    for (int s = 0; s < 4; ++s) {
        s16x8 r;
#pragma unroll
        for (int ii = 0; ii < 8; ++ii)
            r[ii] = (l15 == 0) ? (short)f2bf(wvL[32 * s + 8 * q + ii]) : (short)0;
        wE[s] = r;
    }

    float mi0 = 0.f, mi1 = 0.f;
    float sh0 = 0.f, sh1 = 0.f, sh2 = 0.f;   // per-thread shift partials

    for (int t = 0; t < NTILE; ++t) {
        const int cur = t & 1, nxt = cur ^ 1;
        const int j0 = t * JT;
        const bool more = (t + 1 < NTILE);

        // ---- B1: GEMM1 -> P1 ----
        f32x4 acc[4][2];
#pragma unroll
        for (int m = 0; m < 4; ++m)
#pragma unroll
            for (int r = 0; r < 4; ++r) {
                const float nrm = normL[cur][16 * m + 4 * q + r];
                acc[m][0][r] = fmaf(nrm, w0n0, b1n0);
                acc[m][1][r] = fmaf(nrm, w0n1, b1n1);
            }
        gemm_P<2, FP, false>(&F[cur][0][0], wB1, nullptr, l15, q, acc, nullptr);
        store_P<true>(&P1[0][0], acc, q, uc0);
        __syncthreads();

        // ---- B2: GEMM2 + eacc -> mask -> P2; e + m_i accum (macc dies) ----
        f32x4 macc[4][2];
        f32x4 eacc[4];
#pragma unroll
        for (int m = 0; m < 4; ++m) {
#pragma unroll
            for (int r = 0; r < 4; ++r) { macc[m][0][r] = b2n0; macc[m][1][r] = b2n1; eacc[m][r] = ebias; }
        }
        gemm_P<4, PP, true>(&P1[0][0], wB2, wE, l15, q, macc, eacc);
#pragma unroll
        for (int m = 0; m < 4; ++m)
#pragma unroll
            for (int r = 0; r < 4; ++r)
                if (j0 + 16 * m + 4 * q + r == i) { macc[m][0][r] = 0.f; macc[m][1][r] = 0.f; }
        store_P<false>(&P2[0][0], macc, q, uc0);
#pragma unroll
        for (int m = 0; m < 4; ++m)
#pragma unroll
            for (int r = 0; r < 4; ++r) {
                float ee = 1.f / (1.f + __expf(-eacc[m][r]));  // valid on l15==0
                ee = __shfl(ee, 16 * q);                        // broadcast in q-group
                if (j0 + 16 * m + 4 * q + r == i) ee = 0.f;
                mi0 = fmaf(macc[m][0][r], ee, mi0);
                mi1 = fmaf(macc[m][1][r], ee, mi1);
            }
        __syncthreads();

        // ---- B3: stage-loads for t+1; GEMM3(P2) -> P1 ----
        float4 hv0, hv1, hv2, hv3;
        float sxd0 = 0.f, sxd1 = 0.f, sxd2 = 0.f;
        if (more) {
            const float* hp = &h[(b * NN + j0 + JT + jr) * HDIM + k0];
            hv0 = *(const float4*)hp;
            hv1 = *(const float4*)(hp + 4);
            hv2 = *(const float4*)(hp + 8);
            hv3 = *(const float4*)(hp + 12);
            if (tid < JT) {
                const int j = j0 + JT + tid;
                sxd0 = x[(b * NN + j) * 3 + 0] - xi0;
                sxd1 = x[(b * NN + j) * 3 + 1] - xi1;
                sxd2 = x[(b * NN + j) * 3 + 2] - xi2;
                if (j == i) { sxd0 = 0.f; sxd1 = 0.f; sxd2 = 0.f; }
            }
        }
        f32x4 qacc[4][2];
#pragma unroll
        for (int m = 0; m < 4; ++m)
#pragma unroll
            for (int r = 0; r < 4; ++r) { qacc[m][0][r] = bqn0; qacc[m][1][r] = bqn1; }
        gemm_P<4, PP, false>(&P2[0][0], wB3, nullptr, l15, q, qacc, nullptr);
        store_P<true>(&P1[0][0], qacc, q, uc0);
        __syncthreads();

        // ---- B4: GEMM4 -> racc; staging writes; phi + shift partials ----
        f32x4 racc[4][2];
#pragma unroll
        for (int m = 0; m < 4; ++m)
#pragma unroll
            for (int r = 0; r < 4; ++r) { racc[m][0][r] = brn0; racc[m][1][r] = brn1; }
        gemm_P<4, PP, false>(&P1[0][0], wB4, nullptr, l15, q, racc, nullptr);
        if (more) {
            uint4 pv0, pv1;
            pv0.x = pk2(hv0.x, hv0.y); pv0.y = pk2(hv0.z, hv0.w);
            pv0.z = pk2(hv1.x, hv1.y); pv0.w = pk2(hv1.z, hv1.w);
            pv1.x = pk2(hv2.x, hv2.y); pv1.y = pk2(hv2.z, hv2.w);
            pv1.z = pk2(hv3.x, hv3.y); pv1.w = pk2(hv3.z, hv3.w);
            *(uint4*)&F[nxt][jr][k0]     = pv0;
            *(uint4*)&F[nxt][jr][k0 + 8] = pv1;
            if (tid < JT) {
                diffL[nxt][tid][0] = sxd0; diffL[nxt][tid][1] = sxd1; diffL[nxt][tid][2] = sxd2;
                normL[nxt][tid] = sqrtf(sxd0 * sxd0 + sxd1 * sxd1 + sxd2 * sxd2);
            }
        }
#pragma unroll
        for (int m = 0; m < 4; ++m)
#pragma unroll
            for (int r = 0; r < 4; ++r) {
                const int row = 16 * m + 4 * q + r;
                float p = eluf(racc[m][0][r]) * wx30 + eluf(racc[m][1][r]) * wx31;
                if (w == 0 && l15 == 0) p += bx30;     // bx3 once per row
                if (j0 + row == i) p = 0.f;
                sh0 = fmaf(p, diffL[cur][row][0], sh0);
                sh1 = fmaf(p, diffL[cur][row][1], sh1);
                sh2 = fmaf(p, diffL[cur][row][2], sh2);
            }
        __syncthreads();
    }

    // ---- m_i cross-q reduce -> catL ----
    {
        float v0 = mi0, v1 = mi1;
        v0 += __shfl_xor(v0, 16); v0 += __shfl_xor(v0, 32);
        v1 += __shfl_xor(v1, 16); v1 += __shfl_xor(v1, 32);
        if (lane < 16) {
            catL[uc0]     = v0;
            catL[uc0 + 1] = v1;
        }
    }
    // ---- shift: 64-lane butterfly, then cross-wave via LDS ----
    {
#pragma unroll
        for (int d = 1; d < 64; d <<= 1) {
            sh0 += __shfl_xor(sh0, d);
            sh1 += __shfl_xor(sh1, d);
            sh2 += __shfl_xor(sh2, d);
        }
        if (lane == 0) { shiftL[w][0] = sh0; shiftL[w][1] = sh1; shiftL[w][2] = sh2; }
    }
    if (tid >= 128 && tid < 128 + HDIM)
        catL[UDIM + tid - 128] = h[(b * NN + i) * HDIM + (tid - 128)];
    __syncthreads();

    if (tid < 3) {
        const float inv = 1.f / (float)(NN - 1);
        const float s = shiftL[0][tid] + shiftL[1][tid] + shiftL[2][tid] + shiftL[3][tid];
        out[(b * NN + i) * 3 + tid] = x[(b * NN + i) * 3 + tid] + s * inv;
    }

    // ---- h-MLP epilogue (fp32) ----
    if (tid < UDIM) {
        float s = bh1[tid];
        for (int k = 0; k < UDIM + HDIM; ++k) s = fmaf(catL[k], Wh1[k * UDIM + tid], s);
        th1[tid] = eluf(s);
    }
    __syncthreads();
    if (tid < UDIM) {
        float s = bh2[tid];
        for (int k = 0; k < UDIM; ++k) s = fmaf(th1[k], Wh2[k * UDIM + tid], s);
        th2[tid] = s;
    }
    __syncthreads();
    if (tid < HDIM) {
        float s = bout[tid];
        for (int k = 0; k < UDIM; ++k) s = fmaf(th2[k], Wout[k * HDIM + tid], s);
        out[BB * NN * 3 + (b * NN + i) * HDIM + tid] = s;
    }
}

extern "C" void kernel_launch(void* const* d_in, const int* in_sizes, int n_in,
                              void* d_out, int out_size, void* d_ws, size_t ws_size,
                              hipStream_t stream) {
    const float* x    = (const float*)d_in[0];
    const float* h    = (const float*)d_in[1];
    const float* We1  = (const float*)d_in[2];
    const float* be1  = (const float*)d_in[3];
    const float* We2  = (const float*)d_in[4];
    const float* be2  = (const float*)d_in[5];
    const float* Winf = (const float*)d_in[6];
    const float* binf = (const float*)d_in[7];
    const float* Wx1  = (const float*)d_in[8];
    const float* bx1  = (const float*)d_in[9];
    const float* Wx2  = (const float*)d_in[10];
    const float* bx2  = (const float*)d_in[11];
    const float* Wx3  = (const float*)d_in[12];
    const float* bx3  = (const float*)d_in[13];
    const float* Wh1  = (const float*)d_in[14];
    const float* bh1  = (const float*)d_in[15];
    const float* Wh2  = (const float*)d_in[16];
    const float* bh2  = (const float*)d_in[17];
    const float* Wout = (const float*)d_in[18];
    const float* bout = (const float*)d_in[19];
    float* out = (float*)d_out;

    hipLaunchKernelGGL(egnn_mfma, dim3(BB * NN), dim3(256), 0, stream,
                       x, h, We1, be1, We2, be2, Winf, binf, Wx1, bx1, Wx2, bx2,
                       Wx3, bx3, Wh1, bh1, Wh2, bh2, Wout, bout, out);
}

// Round 9
// 159.262 us; speedup vs baseline: 1.6270x; 1.6270x over previous
//
#include <hip/hip_runtime.h>
#include <math.h>

// EGNN fused kernel, round 9 = r4's register footprint (141us, FETCH 14MB,
// no spill) + arch-register-NEUTRAL barrier reduction 7->4 per tile.
// Allocation model learned r6-r8: reported VGPR_Count=128 is the ARCH half of
// the unified file; 112 weight frags + ~20 scalars fill it. AGPR-class
// (MFMA accumulators) is nearly free; any added arch-class liveness spills.
// Changes vs r4:
//  - e-final via in-wave shfl (lane L owns row L)  [kills eL round-trip]
//  - phi/shift in-register from racc (diff==0 masks row i) [kills P2 store,
//    phi LDS dot, rpartP, per-tile butterfly]
//  - staging contained within ph3 (hv never crosses a barrier)
// Phases: ph1 GEMM1(F)->P1 | ph2 GEMM2(P1)->macc,mask->P2 |
//         ph3 stage-loads; e-partials(P2); stage-writes; GEMM3(P2)->P1 |
//         ph4 e-shfl + m_i (macc dies); GEMM4(P1)->racc; shift partials.

#define BB    2
#define NN    512
#define HDIM  64
#define UDIM  128
#define JT    64
#define NTILE (NN / JT)
#define FP    72    // F row pitch (ushort), 144B
#define PP    136   // P row pitch (ushort), 272B

typedef float f32x4 __attribute__((ext_vector_type(4)));
typedef short s16x8 __attribute__((ext_vector_type(8)));

__device__ __forceinline__ ushort f2bf(float f) {          // setup-path only
    union { float f; unsigned u; } v; v.f = f;
    return (ushort)((v.u + 0x7FFFu + ((v.u >> 16) & 1u)) >> 16);
}
__device__ __forceinline__ unsigned pk2(float lo, float hi) {  // bf16 pair pack
    unsigned r;
    asm("v_cvt_pk_bf16_f32 %0, %1, %2" : "=v"(r) : "v"(lo), "v"(hi));
    return r;
}
__device__ __forceinline__ float bf2f(ushort s) {
    union { unsigned u; float f; } v; v.u = ((unsigned)s) << 16; return v.f;
}
__device__ __forceinline__ f32x4 MFMA(s16x8 a, s16x8 b, f32x4 c) {
    return __builtin_amdgcn_mfma_f32_16x16x32_bf16(a, b, c, 0, 0, 0);
}
__device__ __forceinline__ float eluf(float v) { return v > 0.f ? v : __expf(v) - 1.f; }

__device__ __forceinline__ void load_wfrags(const float* __restrict__ W, int q, int uc0,
                                            s16x8 (&dst)[4][2]) {
#pragma unroll
    for (int s = 0; s < 4; ++s)
#pragma unroll
        for (int n = 0; n < 2; ++n) {
            s16x8 r;
#pragma unroll
            for (int ii = 0; ii < 8; ++ii)
                r[ii] = (short)f2bf(W[(32 * s + 8 * q + ii) * UDIM + uc0 + n]);
            dst[s][n] = r;
        }
}

template <int KSTEPS, int PITCH>
__device__ __forceinline__ void gemm_P(const ushort* __restrict__ P, const s16x8 (&wB)[KSTEPS][2],
                                       int l15, int q, f32x4 (&acc)[4][2]) {
    __builtin_amdgcn_s_setprio(1);
#pragma unroll
    for (int s = 0; s < KSTEPS; ++s) {
        s16x8 a[4];
#pragma unroll
        for (int m = 0; m < 4; ++m)
            a[m] = *(const s16x8*)(P + (16 * m + l15) * PITCH + 32 * s + 8 * q);
#pragma unroll
        for (int m = 0; m < 4; ++m) {
            acc[m][0] = MFMA(a[m], wB[s][0], acc[m][0]);
            acc[m][1] = MFMA(a[m], wB[s][1], acc[m][1]);
        }
    }
    __builtin_amdgcn_s_setprio(0);
}

template <bool ELU>
__device__ __forceinline__ void store_P(ushort* __restrict__ P, const f32x4 (&v)[4][2],
                                        int q, int uc0) {
#pragma unroll
    for (int m = 0; m < 4; ++m)
#pragma unroll
        for (int r = 0; r < 4; ++r) {
            const int row = 16 * m + 4 * q + r;
            float a = v[m][0][r], c = v[m][1][r];
            if (ELU) { a = eluf(a); c = eluf(c); }
            *(unsigned*)(P + row * PP + uc0) = pk2(a, c);
        }
}

__global__ __launch_bounds__(256, 2) void egnn_mfma(
    const float* __restrict__ x, const float* __restrict__ h,
    const float* __restrict__ We1, const float* __restrict__ be1,
    const float* __restrict__ We2, const float* __restrict__ be2,
    const float* __restrict__ Winf, const float* __restrict__ binf,
    const float* __restrict__ Wx1, const float* __restrict__ bx1,
    const float* __restrict__ Wx2, const float* __restrict__ bx2,
    const float* __restrict__ Wx3, const float* __restrict__ bx3,
    const float* __restrict__ Wh1, const float* __restrict__ bh1,
    const float* __restrict__ Wh2, const float* __restrict__ bh2,
    const float* __restrict__ Wout, const float* __restrict__ bout,
    float* __restrict__ out) {
    __shared__ ushort F[2][JT][FP];   // double-buffered feat tile (h_j bf16)
    __shared__ ushort P1[JT][PP];
    __shared__ ushort P2[JT][PP];
    __shared__ float normL[2][JT];
    __shared__ float diffL[2][JT][3];
    __shared__ float rpartE[4][JT];
    __shared__ float bias1L[UDIM];
    __shared__ float WinfL[UDIM];
    __shared__ float shiftL[4][3];
    __shared__ float catL[UDIM + HDIM];
    __shared__ float th1[UDIM], th2[UDIM];

    const int bi = blockIdx.x;
    const int b  = bi >> 9;
    const int i  = bi & (NN - 1);
    const int tid  = threadIdx.x;
    const int lane = tid & 63;
    const int w    = tid >> 6;
    const int l15  = lane & 15;
    const int q    = lane >> 4;
    const int uc0  = 32 * w + 2 * l15;
    const int jr   = tid >> 2, k0 = (tid & 3) * 16;   // staging row/col

    // ---- weight fragments (112 VGPRs, block-lifetime; same as r4) ----
    s16x8 wB1[2][2];                  // We1 rows 1..64 (h_j part)
#pragma unroll
    for (int s = 0; s < 2; ++s)
#pragma unroll
        for (int n = 0; n < 2; ++n) {
            s16x8 r;
#pragma unroll
            for (int ii = 0; ii < 8; ++ii)
                r[ii] = (short)f2bf(We1[(1 + 32 * s + 8 * q + ii) * UDIM + uc0 + n]);
            wB1[s][n] = r;
        }
    s16x8 wB2[4][2], wB3[4][2], wB4[4][2];
    load_wfrags(We2, q, uc0, wB2);
    load_wfrags(Wx1, q, uc0, wB3);
    load_wfrags(Wx2, q, uc0, wB4);

    if (tid < UDIM) {
        WinfL[tid] = Winf[tid];
        float s = be1[tid];
        const float* hi = &h[(b * NN + i) * HDIM];
#pragma unroll 8
        for (int k = 0; k < HDIM; ++k)
            s = fmaf(hi[k], We1[(1 + HDIM + k) * UDIM + tid], s);
        bias1L[tid] = s;              // be1 + h_i @ We1[65:129]
    }
    const float w0n0 = We1[uc0], w0n1 = We1[uc0 + 1];      // norm row of We1
    const float b2n0 = be2[uc0], b2n1 = be2[uc0 + 1];
    const float bqn0 = bx1[uc0], bqn1 = bx1[uc0 + 1];
    const float brn0 = bx2[uc0], brn1 = bx2[uc0 + 1];
    const float wx30 = Wx3[uc0], wx31 = Wx3[uc0 + 1];
    const float binf0 = binf[0], bx30 = bx3[0];
    const float xi0 = x[(b * NN + i) * 3 + 0];
    const float xi1 = x[(b * NN + i) * 3 + 1];
    const float xi2 = x[(b * NN + i) * 3 + 2];

    // ---- prologue: stage tile 0 into buffer 0 ----
    {
        const float* hp = &h[(b * NN + jr) * HDIM + k0];
        const float4 f0 = *(const float4*)hp;
        const float4 f1 = *(const float4*)(hp + 4);
        const float4 f2 = *(const float4*)(hp + 8);
        const float4 f3 = *(const float4*)(hp + 12);
        uint4 pv0, pv1;
        pv0.x = pk2(f0.x, f0.y); pv0.y = pk2(f0.z, f0.w);
        pv0.z = pk2(f1.x, f1.y); pv0.w = pk2(f1.z, f1.w);
        pv1.x = pk2(f2.x, f2.y); pv1.y = pk2(f2.z, f2.w);
        pv1.z = pk2(f3.x, f3.y); pv1.w = pk2(f3.z, f3.w);
        *(uint4*)&F[0][jr][k0]     = pv0;
        *(uint4*)&F[0][jr][k0 + 8] = pv1;
        if (tid < JT) {
            const int j = tid;
            float d0 = x[(b * NN + j) * 3 + 0] - xi0;
            float d1 = x[(b * NN + j) * 3 + 1] - xi1;
            float d2 = x[(b * NN + j) * 3 + 2] - xi2;
            if (j == i) { d0 = 0.f; d1 = 0.f; d2 = 0.f; }
            diffL[0][tid][0] = d0; diffL[0][tid][1] = d1; diffL[0][tid][2] = d2;
            normL[0][tid] = sqrtf(d0 * d0 + d1 * d1 + d2 * d2);
        }
    }
    __syncthreads();                  // bias1L / WinfL / tile-0 staging visible
    const float b1n0 = bias1L[uc0], b1n1 = bias1L[uc0 + 1];

    float mi0 = 0.f, mi1 = 0.f;
    float sh0 = 0.f, sh1 = 0.f, sh2 = 0.f;   // per-thread shift partials

    for (int t = 0; t < NTILE; ++t) {
        const int cur = t & 1, nxt = cur ^ 1;
        const int j0 = t * JT;
        const bool more = (t + 1 < NTILE);

        // ---- ph1: GEMM1 -> P1 ----
        f32x4 acc[4][2];
#pragma unroll
        for (int m = 0; m < 4; ++m)
#pragma unroll
            for (int r = 0; r < 4; ++r) {
                const float nrm = normL[cur][16 * m + 4 * q + r];
                acc[m][0][r] = fmaf(nrm, w0n0, b1n0);
                acc[m][1][r] = fmaf(nrm, w0n1, b1n1);
            }
        gemm_P<2, FP>(&F[cur][0][0], wB1, l15, q, acc);
        store_P<true>(&P1[0][0], acc, q, uc0);
        __syncthreads();

        // ---- ph2: GEMM2 -> m_ij (masked) -> P2 ----
        f32x4 macc[4][2];
#pragma unroll
        for (int m = 0; m < 4; ++m)
#pragma unroll
            for (int r = 0; r < 4; ++r) { macc[m][0][r] = b2n0; macc[m][1][r] = b2n1; }
        gemm_P<4, PP>(&P1[0][0], wB2, l15, q, macc);
#pragma unroll
        for (int m = 0; m < 4; ++m)
#pragma unroll
            for (int r = 0; r < 4; ++r)
                if (j0 + 16 * m + 4 * q + r == i) { macc[m][0][r] = 0.f; macc[m][1][r] = 0.f; }
        store_P<false>(&P2[0][0], macc, q, uc0);
        __syncthreads();

        // ---- ph3: stage loads; e-partials; stage writes; GEMM3 -> P1 ----
        if (more) {
            const float* hp = &h[(b * NN + j0 + JT + jr) * HDIM + k0];
            const float4 f0 = *(const float4*)hp;
            const float4 f1 = *(const float4*)(hp + 4);
            const float4 f2 = *(const float4*)(hp + 8);
            const float4 f3 = *(const float4*)(hp + 12);
            float sxd0 = 0.f, sxd1 = 0.f, sxd2 = 0.f;
            if (tid < JT) {
                const int j = j0 + JT + tid;
                sxd0 = x[(b * NN + j) * 3 + 0] - xi0;
                sxd1 = x[(b * NN + j) * 3 + 1] - xi1;
                sxd2 = x[(b * NN + j) * 3 + 2] - xi2;
                if (j == i) { sxd0 = 0.f; sxd1 = 0.f; sxd2 = 0.f; }
            }
            // e-partials (independent of the loads; hides their latency)
            {
                const int jj = tid & 63, sl = tid >> 6;
                const ushort* pr = &P2[jj][32 * sl];
                float p = 0.f;
#pragma unroll
                for (int cc = 0; cc < 4; ++cc) {
                    const s16x8 mv = *(const s16x8*)(pr + 8 * cc);
#pragma unroll
                    for (int c = 0; c < 8; ++c)
                        p = fmaf(bf2f((ushort)mv[c]), WinfL[32 * sl + 8 * cc + c], p);
                }
                rpartE[sl][jj] = p;
            }
            // staging writes (hv dies here, inside ph3)
            uint4 pv0, pv1;
            pv0.x = pk2(f0.x, f0.y); pv0.y = pk2(f0.z, f0.w);
            pv0.z = pk2(f1.x, f1.y); pv0.w = pk2(f1.z, f1.w);
            pv1.x = pk2(f2.x, f2.y); pv1.y = pk2(f2.z, f2.w);
            pv1.z = pk2(f3.x, f3.y); pv1.w = pk2(f3.z, f3.w);
            *(uint4*)&F[nxt][jr][k0]     = pv0;
            *(uint4*)&F[nxt][jr][k0 + 8] = pv1;
            if (tid < JT) {
                diffL[nxt][tid][0] = sxd0; diffL[nxt][tid][1] = sxd1; diffL[nxt][tid][2] = sxd2;
                normL[nxt][tid] = sqrtf(sxd0 * sxd0 + sxd1 * sxd1 + sxd2 * sxd2);
            }
        } else {
            const int jj = tid & 63, sl = tid >> 6;
            const ushort* pr = &P2[jj][32 * sl];
            float p = 0.f;
#pragma unroll
            for (int cc = 0; cc < 4; ++cc) {
                const s16x8 mv = *(const s16x8*)(pr + 8 * cc);
#pragma unroll
                for (int c = 0; c < 8; ++c)
                    p = fmaf(bf2f((ushort)mv[c]), WinfL[32 * sl + 8 * cc + c], p);
            }
            rpartE[sl][jj] = p;
        }
        f32x4 qacc[4][2];
#pragma unroll
        for (int m = 0; m < 4; ++m)
#pragma unroll
            for (int r = 0; r < 4; ++r) { qacc[m][0][r] = bqn0; qacc[m][1][r] = bqn1; }
        gemm_P<4, PP>(&P2[0][0], wB3, l15, q, qacc);
        store_P<true>(&P1[0][0], qacc, q, uc0);
        __syncthreads();

        // ---- ph4: e via shfl + m_i (macc dies); GEMM4 -> racc; shift ----
        float ev;
        {
            const float es = rpartE[0][lane] + rpartE[1][lane] +
                             rpartE[2][lane] + rpartE[3][lane];
            ev = 1.f / (1.f + __expf(-(es + binf0)));
        }
#pragma unroll
        for (int m = 0; m < 4; ++m)
#pragma unroll
            for (int r = 0; r < 4; ++r) {
                const float e = __shfl(ev, 16 * m + 4 * q + r);
                // macc[row==i] already zeroed -> no e-masking needed
                mi0 = fmaf(macc[m][0][r], e, mi0);
                mi1 = fmaf(macc[m][1][r], e, mi1);
            }
        f32x4 racc[4][2];
#pragma unroll
        for (int m = 0; m < 4; ++m)
#pragma unroll
            for (int r = 0; r < 4; ++r) { racc[m][0][r] = brn0; racc[m][1][r] = brn1; }
        gemm_P<4, PP>(&P1[0][0], wB4, l15, q, racc);
#pragma unroll
        for (int m = 0; m < 4; ++m)
#pragma unroll
            for (int r = 0; r < 4; ++r) {
                const int row = 16 * m + 4 * q + r;
                float p = eluf(racc[m][0][r]) * wx30 + eluf(racc[m][1][r]) * wx31;
                if (w == 0 && l15 == 0) p += bx30;     // bx3 once per row
                // row==i masked by diffL==0
                sh0 = fmaf(p, diffL[cur][row][0], sh0);
                sh1 = fmaf(p, diffL[cur][row][1], sh1);
                sh2 = fmaf(p, diffL[cur][row][2], sh2);
            }
        __syncthreads();
    }

    // ---- m_i cross-q reduce -> catL ----
    {
        float v0 = mi0, v1 = mi1;
        v0 += __shfl_xor(v0, 16); v0 += __shfl_xor(v0, 32);
        v1 += __shfl_xor(v1, 16); v1 += __shfl_xor(v1, 32);
        if (lane < 16) {
            catL[uc0]     = v0;
            catL[uc0 + 1] = v1;
        }
    }
    // ---- shift: 64-lane butterfly, then cross-wave via LDS ----
    {
#pragma unroll
        for (int d = 1; d < 64; d <<= 1) {
            sh0 += __shfl_xor(sh0, d);
            sh1 += __shfl_xor(sh1, d);
            sh2 += __shfl_xor(sh2, d);
        }
        if (lane == 0) { shiftL[w][0] = sh0; shiftL[w][1] = sh1; shiftL[w][2] = sh2; }
    }
    if (tid >= 128 && tid < 128 + HDIM)
        catL[UDIM + tid - 128] = h[(b * NN + i) * HDIM + (tid - 128)];
    __syncthreads();

    if (tid < 3) {
        const float inv = 1.f / (float)(NN - 1);
        const float s = shiftL[0][tid] + shiftL[1][tid] + shiftL[2][tid] + shiftL[3][tid];
        out[(b * NN + i) * 3 + tid] = x[(b * NN + i) * 3 + tid] + s * inv;
    }

    // ---- h-MLP epilogue (fp32) ----
    if (tid < UDIM) {
        float s = bh1[tid];
        for (int k = 0; k < UDIM + HDIM; ++k) s = fmaf(catL[k], Wh1[k * UDIM + tid], s);
        th1[tid] = eluf(s);
    }
    __syncthreads();
    if (tid < UDIM) {
        float s = bh2[tid];
        for (int k = 0; k < UDIM; ++k) s = fmaf(th1[k], Wh2[k * UDIM + tid], s);
        th2[tid] = s;
    }
    __syncthreads();
    if (tid < HDIM) {
        float s = bout[tid];
        for (int k = 0; k < UDIM; ++k) s = fmaf(th2[k], Wout[k * HDIM + tid], s);
        out[BB * NN * 3 + (b * NN + i) * HDIM + tid] = s;
    }
}

extern "C" void kernel_launch(void* const* d_in, const int* in_sizes, int n_in,
                              void* d_out, int out_size, void* d_ws, size_t ws_size,
                              hipStream_t stream) {
    const float* x    = (const float*)d_in[0];
    const float* h    = (const float*)d_in[1];
    const float* We1  = (const float*)d_in[2];
    const float* be1  = (const float*)d_in[3];
    const float* We2  = (const float*)d_in[4];
    const float* be2  = (const float*)d_in[5];
    const float* Winf = (const float*)d_in[6];
    const float* binf = (const float*)d_in[7];
    const float* Wx1  = (const float*)d_in[8];
    const float* bx1  = (const float*)d_in[9];
    const float* Wx2  = (const float*)d_in[10];
    const float* bx2  = (const float*)d_in[11];
    const float* Wx3  = (const float*)d_in[12];
    const float* bx3  = (const float*)d_in[13];
    const float* Wh1  = (const float*)d_in[14];
    const float* bh1  = (const float*)d_in[15];
    const float* Wh2  = (const float*)d_in[16];
    const float* bh2  = (const float*)d_in[17];
    const float* Wout = (const float*)d_in[18];
    const float* bout = (const float*)d_in[19];
    float* out = (float*)d_out;

    hipLaunchKernelGGL(egnn_mfma, dim3(BB * NN), dim3(256), 0, stream,
                       x, h, We1, be1, We2, be2, Winf, binf, Wx1, bx1, Wx2, bx2,
                       Wx3, bx3, Wh1, bh1, Wh2, bh2, Wout, bout, out);
}